// Round 1
// baseline (11012.704 us; speedup 1.0000x reference)
//
#include <hip/hip_runtime.h>

#define TSTEPS 8192
#define H 51
#define G (4 * H)  // 204 gate rows per layer

__device__ __forceinline__ float sigmoidf_fast(float x) {
    float t = __expf(-x);
    return __builtin_amdgcn_rcpf(1.0f + t);
}

__device__ __forceinline__ float tanhf_fast(float x) {
    x = fminf(fmaxf(x, -30.0f), 30.0f);   // avoid inf/inf -> NaN
    float t = __expf(-2.0f * x);
    return (1.0f - t) * __builtin_amdgcn_rcpf(1.0f + t);
}

// One persistent workgroup: 4 waves on one CU, loops all T steps.
// Threads 0..203 each own one gate row (weights register-resident);
// threads 0..50 (wave 0) own the cell updates and the output reduction.
__global__ __launch_bounds__(256, 1)
void lstm2_persistent_kernel(const float* __restrict__ x,
                             const float* __restrict__ Wih1,
                             const float* __restrict__ Whh1,
                             const float* __restrict__ bih1,
                             const float* __restrict__ bhh1,
                             const float* __restrict__ Wih2,
                             const float* __restrict__ Whh2,
                             const float* __restrict__ bih2,
                             const float* __restrict__ bhh2,
                             const float* __restrict__ Wlin,
                             const float* __restrict__ blin,
                             float* __restrict__ out)
{
    __shared__ float sh_h1[H];
    __shared__ float sh_h2[H];
    __shared__ float sh_z1[G];
    __shared__ float sh_z2[G];

    const int tid = threadIdx.x;

    // Register-resident weight rows (threads 0..203).
    float w1[H], w2a[H], w2b[H];
    float b1 = 0.0f, b2 = 0.0f, wx1 = 0.0f;
    if (tid < G) {
        wx1 = Wih1[tid];                     // C == 1: row is a scalar
        b1  = bih1[tid] + bhh1[tid];
        b2  = bih2[tid] + bhh2[tid];
#pragma unroll
        for (int k = 0; k < H; ++k) {
            w1[k]  = Whh1[tid * H + k];
            w2a[k] = Wih2[tid * H + k];
            w2b[k] = Whh2[tid * H + k];
        }
    }
    const float wlin = (tid < H) ? Wlin[tid] : 0.0f;
    const float bl   = blin[0];

    // Persistent cell state in registers of threads 0..50.
    float c1 = 0.0f, c2 = 0.0f;
    if (tid < H) { sh_h1[tid] = 0.0f; sh_h2[tid] = 0.0f; }
    __syncthreads();

    float x_t = x[0];

    for (int t = 0; t < TSTEPS; ++t) {
        // ---- phase 1: z1 = b1 + x_t*wx1 + Whh1 . h1 ----
        if (tid < G) {
            float acc = fmaf(x_t, wx1, b1);
#pragma unroll
            for (int k = 0; k < H; ++k) acc = fmaf(w1[k], sh_h1[k], acc);
            sh_z1[tid] = acc;
        }
        // prefetch next x during the barrier (wraps harmlessly at t==T-1)
        x_t = x[(t + 1) & (TSTEPS - 1)];
        __syncthreads();

        // ---- phase 2: cell-1 update (wave 0, lanes 0..50) ----
        if (tid < H) {
            float ig = sigmoidf_fast(sh_z1[tid]);
            float fg = sigmoidf_fast(sh_z1[tid + H]);
            float gg = tanhf_fast   (sh_z1[tid + 2 * H]);
            float og = sigmoidf_fast(sh_z1[tid + 3 * H]);
            c1 = fg * c1 + ig * gg;
            sh_h1[tid] = og * tanhf_fast(c1);
        }
        __syncthreads();

        // ---- phase 3: z2 = b2 + Wih2 . h1 + Whh2 . h2 ----
        if (tid < G) {
            float acc = b2;
#pragma unroll
            for (int k = 0; k < H; ++k) acc = fmaf(w2a[k], sh_h1[k], acc);
#pragma unroll
            for (int k = 0; k < H; ++k) acc = fmaf(w2b[k], sh_h2[k], acc);
            sh_z2[tid] = acc;
        }
        __syncthreads();

        // ---- phase 4: cell-2 update + output dot (wave 0) ----
        float h2v = 0.0f;
        if (tid < H) {
            float ig = sigmoidf_fast(sh_z2[tid]);
            float fg = sigmoidf_fast(sh_z2[tid + H]);
            float gg = tanhf_fast   (sh_z2[tid + 2 * H]);
            float og = sigmoidf_fast(sh_z2[tid + 3 * H]);
            c2 = fg * c2 + ig * gg;
            h2v = og * tanhf_fast(c2);
            sh_h2[tid] = h2v;
        }
        if (tid < 64) {  // wave 0: reduce h2 . Wlin (lanes >= H contribute 0)
            float p = h2v * wlin;
            p += __shfl_down(p, 32);
            p += __shfl_down(p, 16);
            p += __shfl_down(p, 8);
            p += __shfl_down(p, 4);
            p += __shfl_down(p, 2);
            p += __shfl_down(p, 1);
            if (tid == 0) out[t] = p + bl;
        }
        __syncthreads();
    }
}

extern "C" void kernel_launch(void* const* d_in, const int* in_sizes, int n_in,
                              void* d_out, int out_size, void* d_ws, size_t ws_size,
                              hipStream_t stream) {
    const float* x    = (const float*)d_in[0];
    const float* Wih1 = (const float*)d_in[1];
    const float* Whh1 = (const float*)d_in[2];
    const float* bih1 = (const float*)d_in[3];
    const float* bhh1 = (const float*)d_in[4];
    const float* Wih2 = (const float*)d_in[5];
    const float* Whh2 = (const float*)d_in[6];
    const float* bih2 = (const float*)d_in[7];
    const float* bhh2 = (const float*)d_in[8];
    const float* Wlin = (const float*)d_in[9];
    const float* blin = (const float*)d_in[10];
    float* out = (float*)d_out;

    lstm2_persistent_kernel<<<1, 256, 0, stream>>>(
        x, Wih1, Whh1, bih1, bhh1, Wih2, Whh2, bih2, bhh2, Wlin, blin, out);
}